// Round 1
// baseline (402.087 us; speedup 1.0000x reference)
//
#include <hip/hip_runtime.h>
#include <hip/hip_bf16.h>
#include <cstdint>
#include <cstddef>

#define B_  4
#define T_  2048
#define C_  768
#define NH_ 12
#define HD_ 64

typedef __bf16 bf16_t;
typedef __attribute__((ext_vector_type(8))) __bf16 bf16x8;
typedef __attribute__((ext_vector_type(4))) float floatx4;

#define MFMA16(a, b, c) __builtin_amdgcn_mfma_f32_16x16x32_bf16((a), (b), (c), 0, 0, 0)

// ---------------------------------------------------------------------------
// Input normalization: copy (bf16 case) or downconvert (fp32 case) into ws.
// Discriminator: cos[0][0] == 1.0 exactly. First u16 is 0x3F80 if bf16-stored,
// 0x0000 if fp32-stored (little-endian low half of 0x3F800000).
// ---------------------------------------------------------------------------
__global__ __launch_bounds__(256) void cvt_all_kernel(
    const void* s0, const void* s1, const void* s2, const void* s3,
    const void* s4, const void* s5, const void* s6, const void* s7, const void* s8,
    bf16_t* d0, bf16_t* d1, bf16_t* d2, bf16_t* d3,
    bf16_t* d4, bf16_t* d5, bf16_t* d6, bf16_t* d7, bf16_t* d8)
{
    const void* srcs[9] = {s0, s1, s2, s3, s4, s5, s6, s7, s8};
    bf16_t*     dsts[9] = {d0, d1, d2, d3, d4, d5, d6, d7, d8};
    const int   ns[9]   = {B_*T_*C_, B_*T_*C_, T_*32, T_*32,
                           C_*C_, C_*C_, C_*C_, C_*C_, 144};
    const int t = blockIdx.y;
    const void* src = srcs[t];
    bf16_t*     dst = dsts[t];
    const int   n   = ns[t];
    const bool isf32 = (((const unsigned short*)s2)[0] == 0);
    const int stride = gridDim.x * 256;
    if (isf32) {
        const float* sf = (const float*)src;
        for (int i = blockIdx.x * 256 + threadIdx.x; i < n; i += stride)
            dst[i] = (bf16_t)sf[i];
    } else {
        const unsigned short* sb = (const unsigned short*)src;
        unsigned short* db = (unsigned short*)dst;
        for (int i = blockIdx.x * 256 + threadIdx.x; i < n; i += stride)
            db[i] = sb[i];
    }
}

// ---------------------------------------------------------------------------
// GEMM: C[m][n] = sum_k A[m][k] * Bm[n][k]   (A: MxK row-major, Bm: NxK row-major)
// 128x128 tile, BK=32, 256 threads (4 waves, 2x2 of 64x64), mfma 16x16x32 bf16.
// LDS pitch 40 (16B-aligned, spreads bank starts: m*20 mod 32 hits 8 starts).
// ---------------------------------------------------------------------------
template <bool OUT_BF16>
__device__ __forceinline__ void gemm_bt_tile(
    const bf16_t* __restrict__ A, const bf16_t* __restrict__ Bm,
    void* __restrict__ Cout, int m0, int n0, int K, int ldc)
{
    __shared__ bf16_t As[128 * 40];
    __shared__ bf16_t Bs[128 * 40];
    const int tid  = threadIdx.x;
    const int lane = tid & 63;
    const int wid  = tid >> 6;
    const int m16  = lane & 15;
    const int quad = lane >> 4;
    const int wm   = (wid >> 1) * 64;
    const int wn   = (wid & 1) * 64;

    floatx4 acc[4][4];
#pragma unroll
    for (int i = 0; i < 4; i++)
#pragma unroll
        for (int j = 0; j < 4; j++) acc[i][j] = (floatx4){0.f, 0.f, 0.f, 0.f};

    for (int k0 = 0; k0 < K; k0 += 32) {
#pragma unroll
        for (int tt = 0; tt < 2; tt++) {
            const int c   = tid + tt * 256;   // 512 chunks of 8 elems
            const int row = c >> 2;
            const int cc  = c & 3;
            *(bf16x8*)&As[row * 40 + cc * 8] =
                *(const bf16x8*)&A[(size_t)(m0 + row) * K + k0 + cc * 8];
            *(bf16x8*)&Bs[row * 40 + cc * 8] =
                *(const bf16x8*)&Bm[(size_t)(n0 + row) * K + k0 + cc * 8];
        }
        __syncthreads();
        bf16x8 af[4], bfr[4];
#pragma unroll
        for (int i = 0; i < 4; i++)
            af[i] = *(const bf16x8*)&As[(wm + i * 16 + m16) * 40 + quad * 8];
#pragma unroll
        for (int j = 0; j < 4; j++)
            bfr[j] = *(const bf16x8*)&Bs[(wn + j * 16 + m16) * 40 + quad * 8];
#pragma unroll
        for (int i = 0; i < 4; i++)
#pragma unroll
            for (int j = 0; j < 4; j++)
                acc[i][j] = MFMA16(af[i], bfr[j], acc[i][j]);
        __syncthreads();
    }

    // C/D layout: row = quad*4 + reg, col = lane&15  [m89-verified]
#pragma unroll
    for (int i = 0; i < 4; i++) {
#pragma unroll
        for (int j = 0; j < 4; j++) {
            const int colg = n0 + wn + j * 16 + m16;
#pragma unroll
            for (int r = 0; r < 4; r++) {
                const int rowg = m0 + wm + i * 16 + quad * 4 + r;
                if (OUT_BF16)
                    ((bf16_t*)Cout)[(size_t)rowg * ldc + colg] = (bf16_t)acc[i][j][r];
                else
                    ((float*)Cout)[(size_t)rowg * ldc + colg] = acc[i][j][r];
            }
        }
    }
}

__global__ __launch_bounds__(256) void gemm_qkv_kernel(
    const bf16_t* __restrict__ xb,
    const bf16_t* __restrict__ wq, const bf16_t* __restrict__ wk,
    const bf16_t* __restrict__ wv,
    bf16_t* __restrict__ ql, bf16_t* __restrict__ kl, bf16_t* __restrict__ vl)
{
    const int sel = blockIdx.y / 6;
    const int nt  = blockIdx.y % 6;
    const bf16_t* Bm = (sel == 0) ? wq : (sel == 1) ? wk : wv;
    bf16_t* Cout     = (sel == 0) ? ql : (sel == 1) ? kl : vl;
    gemm_bt_tile<true>(xb, Bm, Cout, blockIdx.x * 128, nt * 128, C_, C_);
}

// out dtype selected at runtime by the same discriminator
__global__ __launch_bounds__(256) void gemm_proj_kernel(
    const bf16_t* __restrict__ yb, const bf16_t* __restrict__ wp,
    void* __restrict__ out, const void* cos_raw)
{
    const bool isf32 = (((const unsigned short*)cos_raw)[0] == 0);
    if (isf32)
        gemm_bt_tile<false>(yb, wp, out, blockIdx.x * 128, blockIdx.y * 128, C_, C_);
    else
        gemm_bt_tile<true>(yb, wp, out, blockIdx.x * 128, blockIdx.y * 128, C_, C_);
}

// ---------------------------------------------------------------------------
// Per-token epilogue: gate = 3*sigmoid(x[:,:12] @ Wg^T); v += gate*ve;
// RoPE(q,k); rms_norm*1.2; write (B,NH,T,HD) bf16 for attention.
// Block = 768 threads = 12 waves; wave h handles head h, lane = d.
// ---------------------------------------------------------------------------
__global__ __launch_bounds__(768) void qkv_post_kernel(
    const bf16_t* __restrict__ x, const bf16_t* __restrict__ ve,
    const bf16_t* __restrict__ cosp, const bf16_t* __restrict__ sinp,
    const bf16_t* __restrict__ wg,
    const bf16_t* __restrict__ ql, const bf16_t* __restrict__ kl,
    const bf16_t* __restrict__ vl,
    bf16_t* __restrict__ qb, bf16_t* __restrict__ kb, bf16_t* __restrict__ vb)
{
    const int bt = blockIdx.x;          // b*T + t
    const int b  = bt / T_;
    const int t  = bt % T_;
    const int h  = threadIdx.x >> 6;
    const int d  = threadIdx.x & 63;
    const size_t lin    = (size_t)bt * C_ + h * HD_ + d;
    const size_t outIdx = ((size_t)(b * NH_ + h) * T_ + t) * HD_ + d;

    // gate
    float g = 0.f;
#pragma unroll
    for (int j = 0; j < 12; j++)
        g += (float)x[(size_t)bt * C_ + j] * (float)wg[h * 12 + j];
    const float gate = 3.f / (1.f + __expf(-g));
    vb[outIdx] = (bf16_t)((float)vl[lin] + gate * (float)ve[lin]);

    const float c = (float)cosp[t * 32 + (d & 31)];
    const float s = (float)sinp[t * 32 + (d & 31)];

    {   // q: rope + rms
        const float own = (float)ql[lin];
        const float oth = __shfl_xor(own, 32, 64);
        const float qr  = (d < 32) ? (own * c - oth * s) : (oth * s + own * c);
        float ss = qr * qr;
#pragma unroll
        for (int off = 1; off < 64; off <<= 1) ss += __shfl_xor(ss, off, 64);
        qb[outIdx] = (bf16_t)(qr * rsqrtf(ss * (1.f / 64.f) + 1e-6f) * 1.2f);
    }
    {   // k: rope + rms
        const float own = (float)kl[lin];
        const float oth = __shfl_xor(own, 32, 64);
        const float kr  = (d < 32) ? (own * c - oth * s) : (oth * s + own * c);
        float ss = kr * kr;
#pragma unroll
        for (int off = 1; off < 64; off <<= 1) ss += __shfl_xor(ss, off, 64);
        kb[outIdx] = (bf16_t)(kr * rsqrtf(ss * (1.f / 64.f) + 1e-6f) * 1.2f);
    }
}

// ---------------------------------------------------------------------------
// Flash attention with sliding window. Block = 64 q-rows (4 waves x 16),
// one (b,h). K processed in 32-key chunks, block-uniform range for barriers.
// QK^T: A-frag = Q[m=lane&15][k=quad*8+j], B-frag = K[n=lane&15][k=quad*8+j].
// P goes C-layout -> LDS -> A-layout (m120-verified transform).
// V staged transposed (Vt[d][k], pitch 40) so PV B-frags are ds_read_b128.
// ---------------------------------------------------------------------------
__global__ __launch_bounds__(256) void attn_kernel(
    const bf16_t* __restrict__ Q, const bf16_t* __restrict__ Km,
    const bf16_t* __restrict__ V, bf16_t* __restrict__ Y,
    const int* __restrict__ wl)
{
    const int qblk = blockIdx.x;
    const int bh   = blockIdx.y;
    const int b    = bh / NH_;
    const int h    = bh % NH_;
    const int window = wl[0];
    const int tid  = threadIdx.x;
    const int wid  = tid >> 6;
    const int lane = tid & 63;
    const int m16  = lane & 15;
    const int quad = lane >> 4;

    const int q0 = qblk * 64;
    const int qw = q0 + wid * 16;

    const size_t base = (size_t)bh * T_ * HD_;
    const bf16_t* Qb = Q + base;
    const bf16_t* Kb = Km + base;
    const bf16_t* Vb = V + base;

    __shared__ bf16_t Ks[32 * 72];       // K chunk, [key][d], pitch 72
    __shared__ bf16_t Vt[64 * 40];       // V chunk transposed, [d][key], pitch 40
    __shared__ bf16_t Ps[4][16 * 40];    // per-wave P tile, pitch 40

    const bf16x8 qf0 = *(const bf16x8*)&Qb[(size_t)(qw + m16) * HD_ + quad * 8];
    const bf16x8 qf1 = *(const bf16x8*)&Qb[(size_t)(qw + m16) * HD_ + 32 + quad * 8];

    floatx4 accO[4];
#pragma unroll
    for (int i = 0; i < 4; i++) accO[i] = (floatx4){0.f, 0.f, 0.f, 0.f};
    float mrow[4] = {-1e30f, -1e30f, -1e30f, -1e30f};
    float lrow[4] = {0.f, 0.f, 0.f, 0.f};

    int lo = q0 - window;
    if (lo < 0) lo = 0;
    lo &= ~31;
    const int nch = (q0 + 64 - lo) >> 5;

    const int sr = tid >> 3;   // 0..31 key row
    const int sc = tid & 7;    // 0..7  dim-octet

    for (int ic = 0; ic < nch; ic++) {
        const int kc = lo + ic * 32;
        // stage K + V^T
        const bf16x8 kv = *(const bf16x8*)&Kb[(size_t)(kc + sr) * HD_ + sc * 8];
        *(bf16x8*)&Ks[sr * 72 + sc * 8] = kv;
        const bf16x8 vv = *(const bf16x8*)&Vb[(size_t)(kc + sr) * HD_ + sc * 8];
#pragma unroll
        for (int j = 0; j < 8; j++) Vt[(sc * 8 + j) * 40 + sr] = vv[j];
        __syncthreads();

        // S = Q K^T  (two 16-key n-tiles, two 32-d k-steps)
        floatx4 sa[2];
#pragma unroll
        for (int nt = 0; nt < 2; nt++) {
            const bf16x8 kf0 = *(const bf16x8*)&Ks[(nt * 16 + m16) * 72 + quad * 8];
            const bf16x8 kf1 = *(const bf16x8*)&Ks[(nt * 16 + m16) * 72 + 32 + quad * 8];
            floatx4 z = (floatx4){0.f, 0.f, 0.f, 0.f};
            z = MFMA16(qf0, kf0, z);
            z = MFMA16(qf1, kf1, z);
            sa[nt] = z;
        }

        // online softmax (per row: row = quad*4 + r, 16 cols live in quad's lanes)
#pragma unroll
        for (int r = 0; r < 4; r++) {
            const int rowg = qw + quad * 4 + r;
#pragma unroll
            for (int nt = 0; nt < 2; nt++) {
                const int colg = kc + nt * 16 + m16;
                float s = sa[nt][r] * 0.125f;
                if (!(rowg >= colg && rowg - colg <= window)) s -= 1e9f;
                sa[nt][r] = s;
            }
            float mx = fmaxf(sa[0][r], sa[1][r]);
#pragma unroll
            for (int off = 1; off < 16; off <<= 1)
                mx = fmaxf(mx, __shfl_xor(mx, off, 64));
            const float mnew  = fmaxf(mrow[r], mx);
            const float alpha = __expf(mrow[r] - mnew);
            float rs = 0.f;
#pragma unroll
            for (int nt = 0; nt < 2; nt++) {
                const float p = __expf(sa[nt][r] - mnew);
                sa[nt][r] = p;
                rs += p;
            }
#pragma unroll
            for (int off = 1; off < 16; off <<= 1)
                rs += __shfl_xor(rs, off, 64);
            lrow[r] = lrow[r] * alpha + rs;
            mrow[r] = mnew;
#pragma unroll
            for (int dt = 0; dt < 4; dt++) accO[dt][r] *= alpha;
        }

        // P: C-layout -> LDS
#pragma unroll
        for (int r = 0; r < 4; r++)
#pragma unroll
            for (int nt = 0; nt < 2; nt++)
                Ps[wid][(quad * 4 + r) * 40 + nt * 16 + m16] = (bf16_t)sa[nt][r];
        __syncthreads();

        // PV: A-frag from Ps, B-frags from Vt
        const bf16x8 pf = *(const bf16x8*)&Ps[wid][m16 * 40 + quad * 8];
#pragma unroll
        for (int dt = 0; dt < 4; dt++) {
            const bf16x8 vf = *(const bf16x8*)&Vt[(dt * 16 + m16) * 40 + quad * 8];
            accO[dt] = MFMA16(pf, vf, accO[dt]);
        }
        __syncthreads();
    }

    // epilogue: divide by l, write Y as (B, T, NH*HD) bf16 for proj GEMM
#pragma unroll
    for (int r = 0; r < 4; r++) {
        const int tq = qw + quad * 4 + r;
        const float inv = 1.f / lrow[r];
#pragma unroll
        for (int dt = 0; dt < 4; dt++)
            Y[((size_t)b * T_ + tq) * C_ + h * HD_ + dt * 16 + m16] =
                (bf16_t)(accO[dt][r] * inv);
    }
}

// ---------------------------------------------------------------------------
extern "C" void kernel_launch(void* const* d_in, const int* in_sizes, int n_in,
                              void* d_out, int out_size, void* d_ws, size_t ws_size,
                              hipStream_t stream)
{
    const void* x_raw   = d_in[0];
    const void* ve_raw  = d_in[1];
    const void* cos_raw = d_in[2];
    const void* sin_raw = d_in[3];
    const void* wq_raw  = d_in[4];
    const void* wk_raw  = d_in[5];
    const void* wv_raw  = d_in[6];
    const void* wp_raw  = d_in[7];
    const void* wg_raw  = d_in[8];
    const int*  wl      = (const int*)d_in[9];

    const size_t NTC = (size_t)B_ * T_ * C_;  // 6291456
    const size_t WSZ = (size_t)C_ * C_;       // 589824

    bf16_t* ws  = (bf16_t*)d_ws;
    bf16_t* xb  = ws;                 // NTC
    bf16_t* veb = xb + NTC;           // NTC
    bf16_t* cb  = veb + NTC;          // 65536
    bf16_t* sb  = cb + T_ * 32;       // 65536
    bf16_t* wqb = sb + T_ * 32;       // WSZ x4
    bf16_t* wkb = wqb + WSZ;
    bf16_t* wvb = wkb + WSZ;
    bf16_t* wpb = wvb + WSZ;
    bf16_t* wgb = wpb + WSZ;          // 144 (pad 256)
    bf16_t* ql  = wgb + 256;          // NTC x3 (pre-rope linear outs)
    bf16_t* kl  = ql + NTC;
    bf16_t* vl  = kl + NTC;
    bf16_t* qb  = vl + NTC;           // NTC x3 (attention-ready)
    bf16_t* kb  = qb + NTC;
    bf16_t* vb  = kb + NTC;
    bf16_t* yb  = ql;                 // reuse: ql dead after qkv_post

    cvt_all_kernel<<<dim3(3072, 9), 256, 0, stream>>>(
        x_raw, ve_raw, cos_raw, sin_raw, wq_raw, wk_raw, wv_raw, wp_raw, wg_raw,
        xb, veb, cb, sb, wqb, wkb, wvb, wpb, wgb);

    gemm_qkv_kernel<<<dim3(64, 18), 256, 0, stream>>>(xb, wqb, wkb, wvb, ql, kl, vl);

    qkv_post_kernel<<<dim3(B_ * T_), 768, 0, stream>>>(
        xb, veb, cb, sb, wgb, ql, kl, vl, qb, kb, vb);

    attn_kernel<<<dim3(T_ / 64, B_ * NH_), 256, 0, stream>>>(qb, kb, vb, yb, wl);

    gemm_proj_kernel<<<dim3(64, 6), 256, 0, stream>>>(yb, wpb, d_out, cos_raw);
}

// Round 2
// 270.653 us; speedup vs baseline: 1.4856x; 1.4856x over previous
//
#include <hip/hip_runtime.h>
#include <hip/hip_bf16.h>
#include <cstdint>
#include <cstddef>

#define B_  4
#define T_  2048
#define C_  768
#define NH_ 12
#define HD_ 64

typedef __bf16 bf16_t;
typedef __attribute__((ext_vector_type(8))) __bf16 bf16x8;
typedef __attribute__((ext_vector_type(4))) __bf16 bf16x4;
typedef __attribute__((ext_vector_type(4))) float floatx4;
typedef __attribute__((ext_vector_type(8))) unsigned short ushort8;
typedef __attribute__((ext_vector_type(4))) unsigned int uint4v;

#define MFMA16(a, b, c) __builtin_amdgcn_mfma_f32_16x16x32_bf16((a), (b), (c), 0, 0, 0)

// exp2 constants: p = exp2(s_raw * 0.125 * log2e - 12 * log2e)
#define SM_C1 0.18033688f
#define SM_C2 -17.3123405f

typedef const __attribute__((address_space(1))) uint8_t* gptr_t;
typedef __attribute__((address_space(3))) uint8_t* lptr_t;

static __device__ __forceinline__ void gld16(const void* g, void* l) {
    // wave-semantic: lane i's 16B goes to (uniform l) + i*16
    __builtin_amdgcn_global_load_lds((gptr_t)g, (lptr_t)l, 16, 0, 0);
}

// ---------------------------------------------------------------------------
// Input normalization (vectorized, 8-elem chunks). Discriminator:
// cos[0][0]==1.0 -> first u16 is 0x3F80 if bf16-stored, 0x0000 if fp32-stored.
// ---------------------------------------------------------------------------
__global__ __launch_bounds__(256) void cvt_all_kernel(
    const void* s0, const void* s1, const void* s2, const void* s3,
    const void* s4, const void* s5, const void* s6, const void* s7, const void* s8,
    bf16_t* d0, bf16_t* d1, bf16_t* d2, bf16_t* d3,
    bf16_t* d4, bf16_t* d5, bf16_t* d6, bf16_t* d7, bf16_t* d8)
{
    const void* srcs[9] = {s0, s1, s2, s3, s4, s5, s6, s7, s8};
    bf16_t*     dsts[9] = {d0, d1, d2, d3, d4, d5, d6, d7, d8};
    const int   ns[9]   = {B_*T_*C_, B_*T_*C_, T_*32, T_*32,
                           C_*C_, C_*C_, C_*C_, C_*C_, 144};
    const int t = blockIdx.y;
    const void* src = srcs[t];
    bf16_t*     dst = dsts[t];
    const int   nc  = ns[t] >> 3;   // 8-elem chunks (all sizes divisible by 8)
    const bool isf32 = (((const unsigned short*)s2)[0] == 0);
    const int stride = gridDim.x * 256;
    if (isf32) {
        const float* sf = (const float*)src;
        for (int i = blockIdx.x * 256 + threadIdx.x; i < nc; i += stride) {
            ushort8 o;
#pragma unroll
            for (int j = 0; j < 8; j++) {
                union { float f; unsigned u; } v; v.f = sf[i * 8 + j];
                bf16_t b = (bf16_t)v.f; (void)b;
                o[j] = (unsigned short)(__builtin_bit_cast(unsigned short,
                         (bf16_t)sf[i * 8 + j]));
            }
            *(ushort8*)&dst[i * 8] = o;
        }
    } else {
        const uint4v* sb = (const uint4v*)src;
        uint4v* db = (uint4v*)dst;
        for (int i = blockIdx.x * 256 + threadIdx.x; i < nc; i += stride)
            db[i] = sb[i];
    }
}

// ---------------------------------------------------------------------------
// GEMM (m97 structure): C[m][n] = sum_k A[m][k] * Bm[n][k]
// 128x128 tile, BK=32, 256 thr (2x2 waves of 64x64), global_load_lds width 16
// into unpadded pitch-32 LDS (conflict-free b128 frag reads).
// ---------------------------------------------------------------------------
template <bool OUT_BF16>
__device__ __forceinline__ void gemm_bt_tile(
    const bf16_t* __restrict__ A, const bf16_t* __restrict__ Bm,
    void* __restrict__ Cout, int m0, int n0, int K, int ldc)
{
    __shared__ bf16_t As[128 * 32];
    __shared__ bf16_t Bs[128 * 32];
    const int tid  = threadIdx.x;
    const int lane = tid & 63;
    const int wid  = tid >> 6;
    const int m16  = lane & 15;
    const int quad = lane >> 4;
    const int wm   = (wid >> 1) * 64;
    const int wn   = (wid & 1) * 64;
    const int srow = lane >> 2;          // 0..15
    const int soct = (lane & 3) * 8;     // 0,8,16,24

    floatx4 acc[4][4];
#pragma unroll
    for (int i = 0; i < 4; i++)
#pragma unroll
        for (int j = 0; j < 4; j++) acc[i][j] = (floatx4){0.f, 0.f, 0.f, 0.f};

    for (int k0 = 0; k0 < K; k0 += 32) {
        // wave w stages rows [16w,16w+16) and [64+16w, 64+16w+16) of each tile
        const bf16_t* ga0 = &A[(size_t)(m0 + 16 * wid + srow) * K + k0 + soct];
        const bf16_t* gb0 = &Bm[(size_t)(n0 + 16 * wid + srow) * K + k0 + soct];
        gld16(ga0,                 (bf16_t*)As + wid * 512);
        gld16(ga0 + (size_t)64 * K, (bf16_t*)As + wid * 512 + 2048);
        gld16(gb0,                 (bf16_t*)Bs + wid * 512);
        gld16(gb0 + (size_t)64 * K, (bf16_t*)Bs + wid * 512 + 2048);
        __syncthreads();
        bf16x8 af[4], bfr[4];
#pragma unroll
        for (int i = 0; i < 4; i++)
            af[i] = *(const bf16x8*)&As[(wm + i * 16 + m16) * 32 + quad * 8];
#pragma unroll
        for (int j = 0; j < 4; j++)
            bfr[j] = *(const bf16x8*)&Bs[(wn + j * 16 + m16) * 32 + quad * 8];
#pragma unroll
        for (int i = 0; i < 4; i++)
#pragma unroll
            for (int j = 0; j < 4; j++)
                acc[i][j] = MFMA16(af[i], bfr[j], acc[i][j]);
        __syncthreads();
    }

    // C/D layout: row = quad*4 + reg, col = lane&15  [m89-verified]
#pragma unroll
    for (int i = 0; i < 4; i++) {
#pragma unroll
        for (int j = 0; j < 4; j++) {
            const int colg = n0 + wn + j * 16 + m16;
#pragma unroll
            for (int r = 0; r < 4; r++) {
                const int rowg = m0 + wm + i * 16 + quad * 4 + r;
                if (OUT_BF16)
                    ((bf16_t*)Cout)[(size_t)rowg * ldc + colg] = (bf16_t)acc[i][j][r];
                else
                    ((float*)Cout)[(size_t)rowg * ldc + colg] = acc[i][j][r];
            }
        }
    }
}

__global__ __launch_bounds__(256) void gemm_qkv_kernel(
    const bf16_t* __restrict__ xb,
    const bf16_t* __restrict__ wq, const bf16_t* __restrict__ wk,
    const bf16_t* __restrict__ wv,
    bf16_t* __restrict__ ql, bf16_t* __restrict__ kl, bf16_t* __restrict__ vl)
{
    const int sel = blockIdx.y / 6;
    const int nt  = blockIdx.y % 6;
    const bf16_t* Bm = (sel == 0) ? wq : (sel == 1) ? wk : wv;
    bf16_t* Cout     = (sel == 0) ? ql : (sel == 1) ? kl : vl;
    gemm_bt_tile<true>(xb, Bm, Cout, blockIdx.x * 128, nt * 128, C_, C_);
}

__global__ __launch_bounds__(256) void gemm_proj_kernel(
    const bf16_t* __restrict__ yb, const bf16_t* __restrict__ wp,
    void* __restrict__ out, const void* cos_raw)
{
    const bool isf32 = (((const unsigned short*)cos_raw)[0] == 0);
    if (isf32)
        gemm_bt_tile<false>(yb, wp, out, blockIdx.x * 128, blockIdx.y * 128, C_, C_);
    else
        gemm_bt_tile<true>(yb, wp, out, blockIdx.x * 128, blockIdx.y * 128, C_, C_);
}

// ---------------------------------------------------------------------------
// Per-token epilogue. Writes Q,K natural [bh][t][d]; V transposed+permuted:
// vt[bh][d][ (t&~63) + perm(t&63) ], perm(c) = ((c&15)<<2)|(c>>4).
// The permutation makes P's packed-b64 column order match V's storage order.
// ---------------------------------------------------------------------------
__global__ __launch_bounds__(768) void qkv_post_kernel(
    const bf16_t* __restrict__ x, const bf16_t* __restrict__ ve,
    const bf16_t* __restrict__ cosp, const bf16_t* __restrict__ sinp,
    const bf16_t* __restrict__ wg,
    const bf16_t* __restrict__ ql, const bf16_t* __restrict__ kl,
    const bf16_t* __restrict__ vl,
    bf16_t* __restrict__ qb, bf16_t* __restrict__ kb, bf16_t* __restrict__ vt)
{
    const int bt = blockIdx.x;          // b*T + t
    const int b  = bt / T_;
    const int t  = bt % T_;
    const int h  = threadIdx.x >> 6;
    const int d  = threadIdx.x & 63;
    const size_t lin    = (size_t)bt * C_ + h * HD_ + d;
    const size_t outIdx = ((size_t)(b * NH_ + h) * T_ + t) * HD_ + d;

    // gate
    float g = 0.f;
#pragma unroll
    for (int j = 0; j < 12; j++)
        g += (float)x[(size_t)bt * C_ + j] * (float)wg[h * 12 + j];
    const float gate = 3.f / (1.f + __expf(-g));
    const int c6 = t & 63;
    const int tp = (t & ~63) | (((c6 & 15) << 2) | (c6 >> 4));
    vt[((size_t)(b * NH_ + h) * HD_ + d) * T_ + tp] =
        (bf16_t)((float)vl[lin] + gate * (float)ve[lin]);

    const float c = (float)cosp[t * 32 + (d & 31)];
    const float s = (float)sinp[t * 32 + (d & 31)];

    {   // q: rope + rms
        const float own = (float)ql[lin];
        const float oth = __shfl_xor(own, 32, 64);
        const float qr  = (d < 32) ? (own * c - oth * s) : (oth * s + own * c);
        float ss = qr * qr;
#pragma unroll
        for (int off = 1; off < 64; off <<= 1) ss += __shfl_xor(ss, off, 64);
        qb[outIdx] = (bf16_t)(qr * rsqrtf(ss * (1.f / 64.f) + 1e-6f) * 1.2f);
    }
    {   // k: rope + rms
        const float own = (float)kl[lin];
        const float oth = __shfl_xor(own, 32, 64);
        const float kr  = (d < 32) ? (own * c - oth * s) : (oth * s + own * c);
        float ss = kr * kr;
#pragma unroll
        for (int off = 1; off < 64; off <<= 1) ss += __shfl_xor(ss, off, 64);
        kb[outIdx] = (bf16_t)(kr * rsqrtf(ss * (1.f / 64.f) + 1e-6f) * 1.2f);
    }
}

// ---------------------------------------------------------------------------
// Flash attention, fixed-SMAX softmax (no running max: rms-normed q,k bound
// scores to < 12; constant shift cancels in O/l).
// Block = 128 q rows, 4 waves x 32 rows (2 m-tiles). 64-key chunks,
// double-buffered LDS, 1 barrier/chunk. K staged natural+XOR-swizzled; V read
// pre-transposed/permuted from global, staged b128+XOR-swizzled; P packed to
// b64 via the column permutation col' = m16*4 + nt.
// ---------------------------------------------------------------------------
__global__ __launch_bounds__(256, 3) void attn_kernel(
    const bf16_t* __restrict__ Q, const bf16_t* __restrict__ Km,
    const bf16_t* __restrict__ Vtg, bf16_t* __restrict__ Y,
    const int* __restrict__ wl)
{
    const int q0 = blockIdx.x * 128;
    const int bh = blockIdx.y;
    const int b  = bh / NH_;
    const int h  = bh % NH_;
    const int window = wl[0];
    const int tid  = threadIdx.x;
    const int wid  = tid >> 6;
    const int lane = tid & 63;
    const int m16  = lane & 15;
    const int quad = lane >> 4;
    const int qw   = q0 + wid * 32;

    const size_t base = (size_t)bh * T_ * HD_;
    const bf16_t* Qb  = Q + base;
    const bf16_t* Kb  = Km + base;
    const bf16_t* Vb  = Vtg + base;   // [d][t] layout

    __shared__ bf16_t Ks[2][64 * 64];
    __shared__ bf16_t Vs[2][64 * 64];
    __shared__ bf16_t Ps[4][32 * 72];

    // Q fragments (held in regs for the whole kernel)
    bf16x8 qf[2][2];
#pragma unroll
    for (int mt = 0; mt < 2; mt++)
#pragma unroll
        for (int ks = 0; ks < 2; ks++)
            qf[mt][ks] = *(const bf16x8*)
                &Qb[(size_t)(qw + mt * 16 + m16) * HD_ + ks * 32 + quad * 8];

    // staging coords: thread -> (row = tid>>2, octet pair = tid&3)
    const int srow = tid >> 2;        // 0..63 (key row for K, d row for V)
    const int soct = tid & 3;         // 0..3
    const int g0   = 2 * soct, g1 = 2 * soct + 1;
    const int kd0  = srow * 64 + ((g0 ^ (srow & 7)) << 3);
    const int kd1  = srow * 64 + ((g1 ^ (srow & 7)) << 3);

    // frag-read swizzle offsets (constant per lane)
    int rsw[2];
#pragma unroll
    for (int ks = 0; ks < 2; ks++)
        rsw[ks] = (((ks * 4 + quad) ^ (m16 & 7)) << 3);

    int lo = q0 - window;
    if (lo < 0) lo = 0;
    lo &= ~63;
    const int nch = (q0 + 128 - lo) >> 6;

    floatx4 accO[2][4];
#pragma unroll
    for (int mt = 0; mt < 2; mt++)
#pragma unroll
        for (int dt = 0; dt < 4; dt++) accO[mt][dt] = (floatx4){0.f, 0.f, 0.f, 0.f};
    float lsum[2][4] = {{0.f, 0.f, 0.f, 0.f}, {0.f, 0.f, 0.f, 0.f}};

    // preload + stage chunk 0
    bf16x8 ka0 = *(const bf16x8*)&Kb[(size_t)(lo + srow) * HD_ + g0 * 8];
    bf16x8 ka1 = *(const bf16x8*)&Kb[(size_t)(lo + srow) * HD_ + g1 * 8];
    bf16x8 va0 = *(const bf16x8*)&Vb[(size_t)srow * T_ + lo + g0 * 8];
    bf16x8 va1 = *(const bf16x8*)&Vb[(size_t)srow * T_ + lo + g1 * 8];
    *(bf16x8*)&Ks[0][kd0] = ka0;
    *(bf16x8*)&Ks[0][kd1] = ka1;
    *(bf16x8*)&Vs[0][kd0] = va0;
    *(bf16x8*)&Vs[0][kd1] = va1;

    for (int ic = 0; ic < nch; ic++) {
        const int kc = lo + ic * 64;
        const bool more = (ic + 1 < nch);
        if (more) {
            const int kn = kc + 64;
            ka0 = *(const bf16x8*)&Kb[(size_t)(kn + srow) * HD_ + g0 * 8];
            ka1 = *(const bf16x8*)&Kb[(size_t)(kn + srow) * HD_ + g1 * 8];
            va0 = *(const bf16x8*)&Vb[(size_t)srow * T_ + kn + g0 * 8];
            va1 = *(const bf16x8*)&Vb[(size_t)srow * T_ + kn + g1 * 8];
        }
        __syncthreads();
        const int buf = ic & 1;

        const bool skip = (kc > qw + 31) || (kc + 63 < qw - window);
        if (!skip) {
            // ---- S = Q K^T ----
            bf16x8 kf[4][2];
#pragma unroll
            for (int nt = 0; nt < 4; nt++) {
                const int rb = (nt * 16 + m16) * 64;
                kf[nt][0] = *(const bf16x8*)&Ks[buf][rb + rsw[0]];
                kf[nt][1] = *(const bf16x8*)&Ks[buf][rb + rsw[1]];
            }
            floatx4 sa[2][4];
#pragma unroll
            for (int mt = 0; mt < 2; mt++)
#pragma unroll
                for (int nt = 0; nt < 4; nt++) {
                    floatx4 z = (floatx4){0.f, 0.f, 0.f, 0.f};
                    z = MFMA16(qf[mt][0], kf[nt][0], z);
                    z = MFMA16(qf[mt][1], kf[nt][1], z);
                    sa[mt][nt] = z;
                }

            // ---- softmax (fixed shift) + packed P write ----
            const bool edge = (kc + 63 > qw) || (kc < qw + 31 - window);
#pragma unroll
            for (int mt = 0; mt < 2; mt++)
#pragma unroll
                for (int r = 0; r < 4; r++) {
                    bf16x4 pk;
                    float psum = 0.f;
                    const int rowg = qw + mt * 16 + quad * 4 + r;
#pragma unroll
                    for (int nt = 0; nt < 4; nt++) {
                        float p = __builtin_amdgcn_exp2f(
                            fmaf(sa[mt][nt][r], SM_C1, SM_C2));
                        if (edge) {
                            const int colg = kc + nt * 16 + m16;
                            const bool ok = (colg <= rowg) &&
                                            (rowg - colg <= window);
                            p = ok ? p : 0.f;
                        }
                        pk[nt] = (bf16_t)p;
                        psum += p;
                    }
                    lsum[mt][r] += psum;
                    *(bf16x4*)&Ps[wid][(mt * 16 + quad * 4 + r) * 72 + m16 * 4] = pk;
                }
            asm volatile("" ::: "memory");  // keep DS order; HW DS is in-order/wave

            // ---- O += P V ----
            bf16x8 pa[2][2];
#pragma unroll
            for (int mt = 0; mt < 2; mt++)
#pragma unroll
                for (int ks = 0; ks < 2; ks++)
                    pa[mt][ks] = *(const bf16x8*)
                        &Ps[wid][(mt * 16 + m16) * 72 + ks * 32 + quad * 8];
#pragma unroll
            for (int dt = 0; dt < 4; dt++) {
                const int rb = (dt * 16 + m16) * 64;
                const bf16x8 vf0 = *(const bf16x8*)&Vs[buf][rb + rsw[0]];
                const bf16x8 vf1 = *(const bf16x8*)&Vs[buf][rb + rsw[1]];
#pragma unroll
                for (int mt = 0; mt < 2; mt++) {
                    accO[mt][dt] = MFMA16(pa[mt][0], vf0, accO[mt][dt]);
                    accO[mt][dt] = MFMA16(pa[mt][1], vf1, accO[mt][dt]);
                }
            }
        }

        if (more) {
            const int nb = buf ^ 1;
            *(bf16x8*)&Ks[nb][kd0] = ka0;
            *(bf16x8*)&Ks[nb][kd1] = ka1;
            *(bf16x8*)&Vs[nb][kd0] = va0;
            *(bf16x8*)&Vs[nb][kd1] = va1;
        }
    }

    // ---- epilogue: reduce l across the 16 lanes of each row, write Y ----
#pragma unroll
    for (int mt = 0; mt < 2; mt++)
#pragma unroll
        for (int r = 0; r < 4; r++) {
            float l = lsum[mt][r];
#pragma unroll
            for (int off = 1; off < 16; off <<= 1) l += __shfl_xor(l, off, 64);
            const float inv = 1.f / l;
            const int tq = qw + mt * 16 + quad * 4 + r;
#pragma unroll
            for (int dt = 0; dt < 4; dt++)
                Y[((size_t)b * T_ + tq) * C_ + h * HD_ + dt * 16 + m16] =
                    (bf16_t)(accO[mt][dt][r] * inv);
        }
}

// ---------------------------------------------------------------------------
extern "C" void kernel_launch(void* const* d_in, const int* in_sizes, int n_in,
                              void* d_out, int out_size, void* d_ws, size_t ws_size,
                              hipStream_t stream)
{
    const void* x_raw   = d_in[0];
    const void* ve_raw  = d_in[1];
    const void* cos_raw = d_in[2];
    const void* sin_raw = d_in[3];
    const void* wq_raw  = d_in[4];
    const void* wk_raw  = d_in[5];
    const void* wv_raw  = d_in[6];
    const void* wp_raw  = d_in[7];
    const void* wg_raw  = d_in[8];
    const int*  wl      = (const int*)d_in[9];

    const size_t NTC = (size_t)B_ * T_ * C_;  // 6291456
    const size_t WSZ = (size_t)C_ * C_;       // 589824

    bf16_t* ws  = (bf16_t*)d_ws;
    bf16_t* xb  = ws;                 // NTC
    bf16_t* veb = xb + NTC;           // NTC
    bf16_t* cb  = veb + NTC;          // 65536
    bf16_t* sb  = cb + T_ * 32;       // 65536
    bf16_t* wqb = sb + T_ * 32;       // WSZ x4
    bf16_t* wkb = wqb + WSZ;
    bf16_t* wvb = wkb + WSZ;
    bf16_t* wpb = wvb + WSZ;
    bf16_t* wgb = wpb + WSZ;          // 144 (pad 256)
    bf16_t* ql  = wgb + 256;          // NTC x3 (pre-rope linear outs)
    bf16_t* kl  = ql + NTC;
    bf16_t* vl  = kl + NTC;
    bf16_t* qb  = vl + NTC;           // NTC x3 (attention-ready)
    bf16_t* kb  = qb + NTC;
    bf16_t* vt  = kb + NTC;           // V^T, [bh][d][t] permuted
    bf16_t* yb  = ql;                 // reuse: ql dead after qkv_post

    cvt_all_kernel<<<dim3(1024, 9), 256, 0, stream>>>(
        x_raw, ve_raw, cos_raw, sin_raw, wq_raw, wk_raw, wv_raw, wp_raw, wg_raw,
        xb, veb, cb, sb, wqb, wkb, wvb, wpb, wgb);

    gemm_qkv_kernel<<<dim3(64, 18), 256, 0, stream>>>(xb, wqb, wkb, wvb, ql, kl, vl);

    qkv_post_kernel<<<dim3(B_ * T_), 768, 0, stream>>>(
        xb, veb, cb, sb, wgb, ql, kl, vl, qb, kb, vt);

    attn_kernel<<<dim3(T_ / 128, B_ * NH_), 256, 0, stream>>>(qb, kb, vt, yb, wl);

    gemm_proj_kernel<<<dim3(64, 6), 256, 0, stream>>>(yb, wpb, d_out, cos_raw);
}

// Round 4
// 257.265 us; speedup vs baseline: 1.5629x; 1.0520x over previous
//
#include <hip/hip_runtime.h>
#include <hip/hip_bf16.h>
#include <cstdint>
#include <cstddef>

#define B_  4
#define T_  2048
#define C_  768
#define NH_ 12
#define HD_ 64

typedef __bf16 bf16_t;
typedef __attribute__((ext_vector_type(8))) __bf16 bf16x8;
typedef __attribute__((ext_vector_type(4))) __bf16 bf16x4;
typedef __attribute__((ext_vector_type(4))) float floatx4;
typedef __attribute__((ext_vector_type(8))) unsigned short ushort8;
typedef __attribute__((ext_vector_type(4))) unsigned int uint4v;

#define MFMA16(a, b, c) __builtin_amdgcn_mfma_f32_16x16x32_bf16((a), (b), (c), 0, 0, 0)

// exp2 constants: p = exp2(s_raw * 0.125 * log2e - 12 * log2e)
#define SM_C1 0.18033688f
#define SM_C2 -17.3123405f

typedef const __attribute__((address_space(1))) uint8_t* gptr_t;
typedef __attribute__((address_space(3))) uint8_t* lptr_t;

static __device__ __forceinline__ void gld16(const void* g, void* l) {
    // per-lane global address; LDS dest = wave-uniform base + lane*16
    __builtin_amdgcn_global_load_lds((gptr_t)g, (lptr_t)l, 16, 0, 0);
}

// ---------------------------------------------------------------------------
// Input normalization (vectorized). Discriminator: cos[0][0]==1.0 -> first
// u16 is 0x3F80 if bf16-stored, 0x0000 if fp32-stored.
// ---------------------------------------------------------------------------
__global__ __launch_bounds__(256) void cvt_all_kernel(
    const void* s0, const void* s1, const void* s2, const void* s3,
    const void* s4, const void* s5, const void* s6, const void* s7, const void* s8,
    bf16_t* d0, bf16_t* d1, bf16_t* d2, bf16_t* d3,
    bf16_t* d4, bf16_t* d5, bf16_t* d6, bf16_t* d7, bf16_t* d8)
{
    const void* srcs[9] = {s0, s1, s2, s3, s4, s5, s6, s7, s8};
    bf16_t*     dsts[9] = {d0, d1, d2, d3, d4, d5, d6, d7, d8};
    const int   ns[9]   = {B_*T_*C_, B_*T_*C_, T_*32, T_*32,
                           C_*C_, C_*C_, C_*C_, C_*C_, 144};
    const int t = blockIdx.y;
    const void* src = srcs[t];
    bf16_t*     dst = dsts[t];
    const int   nc  = ns[t] >> 3;
    const bool isf32 = (((const unsigned short*)s2)[0] == 0);
    const int stride = gridDim.x * 256;
    if (isf32) {
        const float* sf = (const float*)src;
        for (int i = blockIdx.x * 256 + threadIdx.x; i < nc; i += stride) {
            ushort8 o;
#pragma unroll
            for (int j = 0; j < 8; j++)
                o[j] = (unsigned short)__builtin_bit_cast(unsigned short,
                         (bf16_t)sf[i * 8 + j]);
            *(ushort8*)&dst[i * 8] = o;
        }
    } else {
        const uint4v* sb = (const uint4v*)src;
        uint4v* db = (uint4v*)dst;
        for (int i = blockIdx.x * 256 + threadIdx.x; i < nc; i += stride)
            db[i] = sb[i];
    }
}

// ---------------------------------------------------------------------------
// GEMM (m97 structure, BK=64 as 2x32): C[m][n] = sum_k A[m][k] * Bm[n][k]
// 128x128 tile, 256 thr, global_load_lds width 16, half the barriers of BK=32.
// ---------------------------------------------------------------------------
template <bool OUT_BF16>
__device__ __forceinline__ void gemm_bt_tile(
    const bf16_t* __restrict__ A, const bf16_t* __restrict__ Bm,
    void* __restrict__ Cout, int m0, int n0, int K, int ldc)
{
    __shared__ bf16_t As[2][128 * 32];
    __shared__ bf16_t Bs[2][128 * 32];
    const int tid  = threadIdx.x;
    const int lane = tid & 63;
    const int wid  = tid >> 6;
    const int m16  = lane & 15;
    const int quad = lane >> 4;
    const int wm   = (wid >> 1) * 64;
    const int wn   = (wid & 1) * 64;
    const int srow = lane >> 2;          // 0..15
    const int soct = (lane & 3) * 8;     // 0,8,16,24

    floatx4 acc[4][4];
#pragma unroll
    for (int i = 0; i < 4; i++)
#pragma unroll
        for (int j = 0; j < 4; j++) acc[i][j] = (floatx4){0.f, 0.f, 0.f, 0.f};

    for (int k0 = 0; k0 < K; k0 += 64) {
        const bf16_t* ga0 = &A[(size_t)(m0 + 16 * wid + srow) * K + k0 + soct];
        const bf16_t* gb0 = &Bm[(size_t)(n0 + 16 * wid + srow) * K + k0 + soct];
        gld16(ga0,                       (bf16_t*)As[0] + wid * 512);
        gld16(ga0 + (size_t)64 * K,      (bf16_t*)As[0] + wid * 512 + 2048);
        gld16(gb0,                       (bf16_t*)Bs[0] + wid * 512);
        gld16(gb0 + (size_t)64 * K,      (bf16_t*)Bs[0] + wid * 512 + 2048);
        gld16(ga0 + 32,                  (bf16_t*)As[1] + wid * 512);
        gld16(ga0 + (size_t)64 * K + 32, (bf16_t*)As[1] + wid * 512 + 2048);
        gld16(gb0 + 32,                  (bf16_t*)Bs[1] + wid * 512);
        gld16(gb0 + (size_t)64 * K + 32, (bf16_t*)Bs[1] + wid * 512 + 2048);
        __syncthreads();
#pragma unroll
        for (int half = 0; half < 2; half++) {
            bf16x8 af[4], bfr[4];
#pragma unroll
            for (int i = 0; i < 4; i++)
                af[i] = *(const bf16x8*)&As[half][(wm + i * 16 + m16) * 32 + quad * 8];
#pragma unroll
            for (int j = 0; j < 4; j++)
                bfr[j] = *(const bf16x8*)&Bs[half][(wn + j * 16 + m16) * 32 + quad * 8];
#pragma unroll
            for (int i = 0; i < 4; i++)
#pragma unroll
                for (int j = 0; j < 4; j++)
                    acc[i][j] = MFMA16(af[i], bfr[j], acc[i][j]);
        }
        __syncthreads();
    }

    // C/D layout: row = quad*4 + reg, col = lane&15  [m89-verified]
#pragma unroll
    for (int i = 0; i < 4; i++) {
#pragma unroll
        for (int j = 0; j < 4; j++) {
            const int colg = n0 + wn + j * 16 + m16;
#pragma unroll
            for (int r = 0; r < 4; r++) {
                const int rowg = m0 + wm + i * 16 + quad * 4 + r;
                if (OUT_BF16)
                    ((bf16_t*)Cout)[(size_t)rowg * ldc + colg] = (bf16_t)acc[i][j][r];
                else
                    ((float*)Cout)[(size_t)rowg * ldc + colg] = acc[i][j][r];
            }
        }
    }
}

__global__ __launch_bounds__(256) void gemm_qkv_kernel(
    const bf16_t* __restrict__ xb,
    const bf16_t* __restrict__ wq, const bf16_t* __restrict__ wk,
    const bf16_t* __restrict__ wv,
    bf16_t* __restrict__ ql, bf16_t* __restrict__ kl, bf16_t* __restrict__ vl)
{
    const int sel = blockIdx.y / 6;
    const int nt  = blockIdx.y % 6;
    const bf16_t* Bm = (sel == 0) ? wq : (sel == 1) ? wk : wv;
    bf16_t* Cout     = (sel == 0) ? ql : (sel == 1) ? kl : vl;
    gemm_bt_tile<true>(xb, Bm, Cout, blockIdx.x * 128, nt * 128, C_, C_);
}

__global__ __launch_bounds__(256) void gemm_proj_kernel(
    const bf16_t* __restrict__ yb, const bf16_t* __restrict__ wp,
    void* __restrict__ out, const void* cos_raw)
{
    const bool isf32 = (((const unsigned short*)cos_raw)[0] == 0);
    if (isf32)
        gemm_bt_tile<false>(yb, wp, out, blockIdx.x * 128, blockIdx.y * 128, C_, C_);
    else
        gemm_bt_tile<true>(yb, wp, out, blockIdx.x * 128, blockIdx.y * 128, C_, C_);
}

// ---------------------------------------------------------------------------
// Per-token epilogue. Grid (T/32, B, 3), 256 thr; wave w -> head z*4+w,
// 32 tokens. Q,K: rope+rms, coalesced. V: gate+add into wave-private fp32
// LDS tile (pitch 65), then coalesced transposed write to
// vt[bh][d][ (t&~31) | p(t&31) ], p(c) = ((c>>2)&3)*8 + (c>>4)*4 + (c&3):
// the PV A-frag pairing permutation (see attn_kernel).
// ---------------------------------------------------------------------------
__global__ __launch_bounds__(256) void qkv_post_kernel(
    const bf16_t* __restrict__ x, const bf16_t* __restrict__ ve,
    const bf16_t* __restrict__ cosp, const bf16_t* __restrict__ sinp,
    const bf16_t* __restrict__ wg,
    const bf16_t* __restrict__ ql, const bf16_t* __restrict__ kl,
    const bf16_t* __restrict__ vl,
    bf16_t* __restrict__ qb, bf16_t* __restrict__ kb, bf16_t* __restrict__ vt)
{
    const int t0 = blockIdx.x * 32;
    const int b  = blockIdx.y;
    const int w  = threadIdx.x >> 6;
    const int h  = blockIdx.z * 4 + w;
    const int d  = threadIdx.x & 63;
    __shared__ float vtile[4][32 * 65];
    float* vt_l = vtile[w];
    const float wgd = (d < 12) ? (float)wg[h * 12 + d] : 0.f;

    for (int c = 0; c < 32; c++) {
        const int t  = t0 + c;
        const int bt = b * T_ + t;
        const size_t lin = (size_t)bt * C_ + h * HD_ + d;
        float gx = (d < 12) ? (float)x[(size_t)bt * C_ + d] * wgd : 0.f;
        gx += __shfl_xor(gx, 1, 64); gx += __shfl_xor(gx, 2, 64);
        gx += __shfl_xor(gx, 4, 64); gx += __shfl_xor(gx, 8, 64);
        gx = __shfl(gx, 0, 64);
        const float gate = 3.f / (1.f + __expf(-gx));
        vt_l[c * 65 + d] = (float)vl[lin] + gate * (float)ve[lin];

        const float co = (float)cosp[t * 32 + (d & 31)];
        const float si = (float)sinp[t * 32 + (d & 31)];
        const size_t oidx = ((size_t)(b * NH_ + h) * T_ + t) * HD_ + d;
        {
            const float own = (float)ql[lin];
            const float oth = __shfl_xor(own, 32, 64);
            const float qr  = (d < 32) ? (own * co - oth * si) : (oth * si + own * co);
            float ss = qr * qr;
#pragma unroll
            for (int off = 1; off < 64; off <<= 1) ss += __shfl_xor(ss, off, 64);
            qb[oidx] = (bf16_t)(qr * rsqrtf(ss * (1.f / 64.f) + 1e-6f) * 1.2f);
        }
        {
            const float own = (float)kl[lin];
            const float oth = __shfl_xor(own, 32, 64);
            const float kr  = (d < 32) ? (own * co - oth * si) : (oth * si + own * co);
            float ss = kr * kr;
#pragma unroll
            for (int off = 1; off < 64; off <<= 1) ss += __shfl_xor(ss, off, 64);
            kb[oidx] = (bf16_t)(kr * rsqrtf(ss * (1.f / 64.f) + 1e-6f) * 1.2f);
        }
    }

    // coalesced transposed V write (perm within each 32-token group)
    const int cc = threadIdx.x & 31;
    const int dh = (threadIdx.x >> 5) & 1;
    const int tp = t0 + ((((cc >> 2) & 3) << 3) | ((cc >> 4) << 2) | (cc & 3));
#pragma unroll 4
    for (int it = 0; it < 32; it++) {
        const int dd = it * 2 + dh;
        vt[((size_t)(b * NH_ + h) * HD_ + dd) * T_ + tp] =
            (bf16_t)vt_l[cc * 65 + dd];
    }
}

// ---------------------------------------------------------------------------
// Flash attention, fixed-SMAX softmax. S^T = MFMA(A=K, B=Q): C layout gives
// lane m16 = query, regs = 4 keys (quad*4+r) -> P stays in registers.
// PV: pair adjacent 16-key tiles into one 16x16x32 MFMA; A = pk[nt]||pk[nt+1]
// (keys quad*8+j), valid because V^T columns are stored permuted by
// p(c) = ((c>>2)&3)*8 + (c>>4)*4 + (c&3) per 32-token group.
// Per-(mt,nt) wave-uniform skip; zero-fill pk for masked tiles in live pairs.
// Balanced qblk permutation per dispatch generation (critical CU 54->44).
// ---------------------------------------------------------------------------
__global__ __launch_bounds__(256, 3) void attn_kernel(
    const bf16_t* __restrict__ Q, const bf16_t* __restrict__ Km,
    const bf16_t* __restrict__ Vtg, bf16_t* __restrict__ Y,
    const int* __restrict__ wl)
{
    const int bx   = blockIdx.x;
    const int bh   = blockIdx.y;
    const int gsel = bh >> 4;      // dispatch generation (256-block groups)
    int qblk;
    if (gsel == 0)      qblk = bx;
    else if (gsel == 1) qblk = 15 - bx;
    else                qblk = (int)((0xECA8642013579BDFull >> (bx * 4)) & 0xF);
    const int q0 = qblk * 128;
    const int b  = bh / NH_;
    const int h  = bh % NH_;
    const int window = wl[0];
    const int tid  = threadIdx.x;
    const int wid  = tid >> 6;
    const int lane = tid & 63;
    const int m16  = lane & 15;
    const int quad = lane >> 4;
    const int qw   = q0 + wid * 32;

    const size_t base = (size_t)bh * T_ * HD_;
    const bf16_t* Qb  = Q + base;
    const bf16_t* Kb  = Km + base;
    const bf16_t* Vb  = Vtg + base;   // [d][t-permuted] layout

    __shared__ bf16_t Ks[2][64 * 64];
    __shared__ bf16_t Vs[2][64 * 64];

    // Q fragments (B operand: lane m16 = query col, k = quad*8+j over d)
    bf16x8 qf[2][2];
#pragma unroll
    for (int mt = 0; mt < 2; mt++)
#pragma unroll
        for (int ks = 0; ks < 2; ks++)
            qf[mt][ks] = *(const bf16x8*)
                &Qb[(size_t)(qw + mt * 16 + m16) * HD_ + ks * 32 + quad * 8];

    // staging: thread -> (row = tid>>2, two octets), XOR-swizzled columns
    const int srow = tid >> 2;
    const int soct = tid & 3;
    const int g0   = 2 * soct, g1 = 2 * soct + 1;
    const int kd0  = srow * 64 + ((g0 ^ (srow & 7)) << 3);
    const int kd1  = srow * 64 + ((g1 ^ (srow & 7)) << 3);
    int rsw[2];
#pragma unroll
    for (int ks = 0; ks < 2; ks++)
        rsw[ks] = (((ks * 4 + quad) ^ (m16 & 7)) << 3);

    int lo = q0 - window;
    if (lo < 0) lo = 0;
    lo &= ~63;
    const int nch = (q0 + 128 - lo) >> 6;

    floatx4 accO[2][4];
#pragma unroll
    for (int mt = 0; mt < 2; mt++)
#pragma unroll
        for (int dt = 0; dt < 4; dt++) accO[mt][dt] = (floatx4){0.f, 0.f, 0.f, 0.f};
    float lsum[2] = {0.f, 0.f};
    const bf16x4 zero4 = {(bf16_t)0.f, (bf16_t)0.f, (bf16_t)0.f, (bf16_t)0.f};

    // preload + stage chunk 0
    bf16x8 ka0 = *(const bf16x8*)&Kb[(size_t)(lo + srow) * HD_ + g0 * 8];
    bf16x8 ka1 = *(const bf16x8*)&Kb[(size_t)(lo + srow) * HD_ + g1 * 8];
    bf16x8 va0 = *(const bf16x8*)&Vb[(size_t)srow * T_ + lo + g0 * 8];
    bf16x8 va1 = *(const bf16x8*)&Vb[(size_t)srow * T_ + lo + g1 * 8];
    *(bf16x8*)&Ks[0][kd0] = ka0;
    *(bf16x8*)&Ks[0][kd1] = ka1;
    *(bf16x8*)&Vs[0][kd0] = va0;
    *(bf16x8*)&Vs[0][kd1] = va1;

    for (int ic = 0; ic < nch; ic++) {
        const int kc = lo + ic * 64;
        const bool more = (ic + 1 < nch);
        if (more) {
            const int kn = kc + 64;
            ka0 = *(const bf16x8*)&Kb[(size_t)(kn + srow) * HD_ + g0 * 8];
            ka1 = *(const bf16x8*)&Kb[(size_t)(kn + srow) * HD_ + g1 * 8];
            va0 = *(const bf16x8*)&Vb[(size_t)srow * T_ + kn + g0 * 8];
            va1 = *(const bf16x8*)&Vb[(size_t)srow * T_ + kn + g1 * 8];
        }
        __syncthreads();
        const int buf = ic & 1;

        const bool skip = (kc > qw + 31) || (kc + 63 < qw - window);
        if (!skip) {
            // K frags (A operand: lane m16 = key row)
            bf16x8 kf[4][2];
#pragma unroll
            for (int nt = 0; nt < 4; nt++) {
                const int rb = (nt * 16 + m16) * 64;
                kf[nt][0] = *(const bf16x8*)&Ks[buf][rb + rsw[0]];
                kf[nt][1] = *(const bf16x8*)&Ks[buf][rb + rsw[1]];
            }
            // S^T = K Q^T, exp, pack into A-frag quarters (no LDS round-trip)
            bf16x4 pk[2][4];
            unsigned livemask = 0;
#pragma unroll
            for (int mt = 0; mt < 2; mt++) {
                const int qmin = qw + mt * 16, qmax = qmin + 15;
                float lacc = 0.f;
#pragma unroll
                for (int nt = 0; nt < 4; nt++) {
                    const int kmin = kc + nt * 16, kmax = kmin + 15;
                    if (kmin > qmax || kmax < qmin - window) {
                        pk[mt][nt] = zero4;
                        continue;
                    }
                    livemask |= 1u << (mt * 4 + nt);
                    floatx4 z = (floatx4){0.f, 0.f, 0.f, 0.f};
                    z = MFMA16(kf[nt][0], qf[mt][0], z);
                    z = MFMA16(kf[nt][1], qf[mt][1], z);
                    const bool edge = (kmax > qmin) || (kmin < qmax - window);
                    const int query = qmin + m16;
                    bf16x4 t4;
#pragma unroll
                    for (int r = 0; r < 4; r++) {
                        float p = __builtin_amdgcn_exp2f(
                            fmaf(z[r], SM_C1, SM_C2));
                        if (edge) {
                            const int key = kmin + quad * 4 + r;
                            const bool ok = (key <= query) &&
                                            (query - key <= window);
                            p = ok ? p : 0.f;
                        }
                        t4[r] = (bf16_t)p;
                        lacc += p;
                    }
                    pk[mt][nt] = t4;
                }
                lsum[mt] += lacc;
            }
            // O += P V  (paired K=32 MFMAs; V columns pre-permuted)
#pragma unroll
            for (int pr = 0; pr < 2; pr++) {
                const unsigned pm0 = (livemask >> (2 * pr)) & 3u;
                const unsigned pm1 = (livemask >> (4 + 2 * pr)) & 3u;
                if (!(pm0 | pm1)) continue;
                const bf16x8 pa0 = __builtin_shufflevector(
                    pk[0][2 * pr], pk[0][2 * pr + 1], 0, 1, 2, 3, 4, 5, 6, 7);
                const bf16x8 pa1 = __builtin_shufflevector(
                    pk[1][2 * pr], pk[1][2 * pr + 1], 0, 1, 2, 3, 4, 5, 6, 7);
                const int vco = (((pr * 4 + quad) ^ (m16 & 7)) << 3);
#pragma unroll
                for (int dt = 0; dt < 4; dt++) {
                    const bf16x8 vf = *(const bf16x8*)
                        &Vs[buf][(dt * 16 + m16) * 64 + vco];
                    if (pm0) accO[0][dt] = MFMA16(pa0, vf, accO[0][dt]);
                    if (pm1) accO[1][dt] = MFMA16(pa1, vf, accO[1][dt]);
                }
            }
        }

        if (more) {
            const int nb = buf ^ 1;
            *(bf16x8*)&Ks[nb][kd0] = ka0;
            *(bf16x8*)&Ks[nb][kd1] = ka1;
            *(bf16x8*)&Vs[nb][kd0] = va0;
            *(bf16x8*)&Vs[nb][kd1] = va1;
        }
    }

    // epilogue: O rows = quad*4+r (query), cols = m16 (d); l lives at lane m16
#pragma unroll
    for (int mt = 0; mt < 2; mt++) {
        float red = lsum[mt];
        red += __shfl_xor(red, 16, 64);
        red += __shfl_xor(red, 32, 64);
#pragma unroll
        for (int r = 0; r < 4; r++) {
            const float lq  = __shfl(red, quad * 4 + r, 64);
            const float inv = 1.f / lq;
            const int   tq  = qw + mt * 16 + quad * 4 + r;
#pragma unroll
            for (int dt = 0; dt < 4; dt++)
                Y[((size_t)b * T_ + tq) * C_ + h * HD_ + dt * 16 + m16] =
                    (bf16_t)(accO[mt][dt][r] * inv);
        }
    }
}

// ---------------------------------------------------------------------------
extern "C" void kernel_launch(void* const* d_in, const int* in_sizes, int n_in,
                              void* d_out, int out_size, void* d_ws, size_t ws_size,
                              hipStream_t stream)
{
    const void* x_raw   = d_in[0];
    const void* ve_raw  = d_in[1];
    const void* cos_raw = d_in[2];
    const void* sin_raw = d_in[3];
    const void* wq_raw  = d_in[4];
    const void* wk_raw  = d_in[5];
    const void* wv_raw  = d_in[6];
    const void* wp_raw  = d_in[7];
    const void* wg_raw  = d_in[8];
    const int*  wl      = (const int*)d_in[9];

    const size_t NTC = (size_t)B_ * T_ * C_;  // 6291456
    const size_t WSZ = (size_t)C_ * C_;       // 589824

    bf16_t* ws  = (bf16_t*)d_ws;
    bf16_t* xb  = ws;                 // NTC
    bf16_t* veb = xb + NTC;           // NTC
    bf16_t* cb  = veb + NTC;          // 65536
    bf16_t* sb  = cb + T_ * 32;       // 65536
    bf16_t* wqb = sb + T_ * 32;       // WSZ x4
    bf16_t* wkb = wqb + WSZ;
    bf16_t* wvb = wkb + WSZ;
    bf16_t* wpb = wvb + WSZ;
    bf16_t* wgb = wpb + WSZ;          // 144 (pad 256)
    bf16_t* ql  = wgb + 256;          // NTC x3 (pre-rope linear outs)
    bf16_t* kl  = ql + NTC;
    bf16_t* vl  = kl + NTC;
    bf16_t* qb  = vl + NTC;           // NTC x3 (attention-ready)
    bf16_t* kb  = qb + NTC;
    bf16_t* vt  = kb + NTC;           // V^T, [bh][d][t-permuted]
    bf16_t* yb  = ql;                 // reuse: ql dead after qkv_post

    cvt_all_kernel<<<dim3(1024, 9), 256, 0, stream>>>(
        x_raw, ve_raw, cos_raw, sin_raw, wq_raw, wk_raw, wv_raw, wp_raw, wg_raw,
        xb, veb, cb, sb, wqb, wkb, wvb, wpb, wgb);

    gemm_qkv_kernel<<<dim3(64, 18), 256, 0, stream>>>(xb, wqb, wkb, wvb, ql, kl, vl);

    qkv_post_kernel<<<dim3(T_ / 32, B_, 3), 256, 0, stream>>>(
        xb, veb, cb, sb, wgb, ql, kl, vl, qb, kb, vt);

    attn_kernel<<<dim3(16, 48), 256, 0, stream>>>(qb, kb, vt, yb, wl);

    gemm_proj_kernel<<<dim3(64, 6), 256, 0, stream>>>(yb, wpb, d_out, cos_raw);
}

// Round 6
// 247.931 us; speedup vs baseline: 1.6218x; 1.0376x over previous
//
#include <hip/hip_runtime.h>
#include <hip/hip_bf16.h>
#include <cstdint>
#include <cstddef>

#define B_  4
#define T_  2048
#define C_  768
#define NH_ 12
#define HD_ 64

typedef __bf16 bf16_t;
typedef __attribute__((ext_vector_type(8))) __bf16 bf16x8;
typedef __attribute__((ext_vector_type(4))) __bf16 bf16x4;
typedef __attribute__((ext_vector_type(4))) float floatx4;
typedef __attribute__((ext_vector_type(8))) unsigned short ushort8;

#define MFMA16(a, b, c) __builtin_amdgcn_mfma_f32_16x16x32_bf16((a), (b), (c), 0, 0, 0)

// exp2 constants: p = exp2(s_raw * 0.125 * log2e - 12 * log2e)
#define SM_C1 0.18033688f
#define SM_C2 -17.3123405f

typedef const __attribute__((address_space(1))) uint8_t* gptr_t;
typedef __attribute__((address_space(3))) uint8_t* lptr_t;

static __device__ __forceinline__ void gld16(const void* g, void* l) {
    // per-lane global address; LDS dest = wave-uniform base + lane*16
    __builtin_amdgcn_global_load_lds((gptr_t)g, (lptr_t)l, 16, 0, 0);
}

static __device__ __forceinline__ float bfl(unsigned p) {       // low bf16 -> f32
    return __builtin_bit_cast(float, p << 16);
}
static __device__ __forceinline__ float bfh(unsigned p) {       // high bf16 -> f32
    return __builtin_bit_cast(float, p & 0xffff0000u);
}

// ---------------------------------------------------------------------------
// fp32 fallback conversion only (bf16 case: all kernels read raw inputs).
// Discriminator: cos[0][0]==1.0 -> first u16 0x3F80 if bf16, 0x0000 if fp32.
// ---------------------------------------------------------------------------
__global__ __launch_bounds__(256) void cvt_all_kernel(
    const void* s0, const void* s1, const void* s2, const void* s3,
    const void* s4, const void* s5, const void* s6, const void* s7, const void* s8,
    bf16_t* d0, bf16_t* d1, bf16_t* d2, bf16_t* d3,
    bf16_t* d4, bf16_t* d5, bf16_t* d6, bf16_t* d7, bf16_t* d8)
{
    const bool isf32 = (((const unsigned short*)s2)[0] == 0);
    if (!isf32) return;
    const void* srcs[9] = {s0, s1, s2, s3, s4, s5, s6, s7, s8};
    bf16_t*     dsts[9] = {d0, d1, d2, d3, d4, d5, d6, d7, d8};
    const int   ns[9]   = {B_*T_*C_, B_*T_*C_, T_*32, T_*32,
                           C_*C_, C_*C_, C_*C_, C_*C_, 144};
    const int t = blockIdx.y;
    const float* sf = (const float*)srcs[t];
    bf16_t*     dst = dsts[t];
    const int   nc  = ns[t] >> 3;
    const int stride = gridDim.x * 256;
    for (int i = blockIdx.x * 256 + threadIdx.x; i < nc; i += stride) {
        ushort8 o;
#pragma unroll
        for (int j = 0; j < 8; j++)
            o[j] = (unsigned short)__builtin_bit_cast(unsigned short,
                     (bf16_t)sf[i * 8 + j]);
        *(ushort8*)&dst[i * 8] = o;
    }
}

// ---------------------------------------------------------------------------
// Fused QKV GEMM + rope/rms (Q,K) + gate/ve (V).
// 128x128 tile, BK=64, proven m97 staging. Outputs:
//   qn,kn: [b][t][C] rope+rms'd bf16 ; vt: [b*12+h][d][t-perm] bf16.
// V epilogue does NO LDS transpose: token c = i*16+quad*4+r maps to permuted
// slot (i>>1)*32 + quad*8 + (i&1)*4 + r -- consecutive in r -> direct bf16x4
// global stores (perm identical to the round-4-verified one).
// ---------------------------------------------------------------------------
__global__ __launch_bounds__(256) void gemm_qkv_fused(
    const void* xr,  const bf16_t* xc,
    const void* wqr, const bf16_t* wqc,
    const void* wkr, const bf16_t* wkc,
    const void* wvr, const bf16_t* wvc,
    const void* cr,  const bf16_t* ccv,
    const void* sr,  const bf16_t* scv,
    const void* ver, const bf16_t* vec,
    const void* wgr, const bf16_t* wgc,
    bf16_t* qn, bf16_t* kn, bf16_t* vt)
{
    __shared__ alignas(16) char sm[36864];
    const bool f32 = (((const unsigned short*)cr)[0] == 0);
    const bf16_t* X  = f32 ? xc  : (const bf16_t*)xr;
    const bf16_t* WQ = f32 ? wqc : (const bf16_t*)wqr;
    const bf16_t* WK = f32 ? wkc : (const bf16_t*)wkr;
    const bf16_t* WV = f32 ? wvc : (const bf16_t*)wvr;
    const bf16_t* CC = f32 ? ccv : (const bf16_t*)cr;
    const bf16_t* SS = f32 ? scv : (const bf16_t*)sr;
    const bf16_t* VE = f32 ? vec : (const bf16_t*)ver;
    const bf16_t* WG = f32 ? wgc : (const bf16_t*)wgr;

    const int sel = blockIdx.y / 6;          // 0=Q 1=K 2=V
    const int nt  = blockIdx.y % 6;
    const int m0  = blockIdx.x * 128;
    const int n0  = nt * 128;
    const bf16_t* Bm = (sel == 0) ? WQ : (sel == 1) ? WK : WV;

    bf16_t* As = (bf16_t*)sm;                // 2 halves of [128][32]
    bf16_t* Bs = (bf16_t*)(sm + 16384);

    const int tid  = threadIdx.x;
    const int lane = tid & 63;
    const int wid  = tid >> 6;
    const int m16  = lane & 15;
    const int quad = lane >> 4;
    const int wm   = (wid >> 1) * 64;
    const int wn   = (wid & 1) * 64;
    const int srow = lane >> 2;
    const int soct = (lane & 3) * 8;

    floatx4 acc[4][4];
#pragma unroll
    for (int i = 0; i < 4; i++)
#pragma unroll
        for (int j = 0; j < 4; j++) acc[i][j] = (floatx4){0.f, 0.f, 0.f, 0.f};

    for (int k0 = 0; k0 < C_; k0 += 64) {
        const bf16_t* ga0 = &X[(size_t)(m0 + 16 * wid + srow) * C_ + k0 + soct];
        const bf16_t* gb0 = &Bm[(size_t)(n0 + 16 * wid + srow) * C_ + k0 + soct];
        gld16(ga0,                        As + wid * 512);
        gld16(ga0 + (size_t)64 * C_,      As + wid * 512 + 2048);
        gld16(gb0,                        Bs + wid * 512);
        gld16(gb0 + (size_t)64 * C_,      Bs + wid * 512 + 2048);
        gld16(ga0 + 32,                   As + 4096 + wid * 512);
        gld16(ga0 + (size_t)64 * C_ + 32, As + 4096 + wid * 512 + 2048);
        gld16(gb0 + 32,                   Bs + 4096 + wid * 512);
        gld16(gb0 + (size_t)64 * C_ + 32, Bs + 4096 + wid * 512 + 2048);
        __syncthreads();
#pragma unroll
        for (int half = 0; half < 2; half++) {
            bf16x8 af[4], bfr[4];
#pragma unroll
            for (int i = 0; i < 4; i++)
                af[i] = *(const bf16x8*)&As[half * 4096 + (wm + i * 16 + m16) * 32 + quad * 8];
#pragma unroll
            for (int j = 0; j < 4; j++)
                bfr[j] = *(const bf16x8*)&Bs[half * 4096 + (wn + j * 16 + m16) * 32 + quad * 8];
#pragma unroll
            for (int i = 0; i < 4; i++)
#pragma unroll
                for (int j = 0; j < 4; j++)
                    acc[i][j] = MFMA16(af[i], bfr[j], acc[i][j]);
        }
        __syncthreads();
    }

    if (sel < 2) {
        // ---- Q/K epilogue: rope + rms, store [b][t][C] ----
        unsigned* csT = (unsigned*)sm;       // [128][33] packed (cos | sin<<16)
        const int tbase = m0 & 2047;
        for (int idx = tid; idx < 128 * 32; idx += 256) {
            const int rr = idx >> 5, dd = idx & 31;
            const unsigned cv = ((const unsigned short*)CC)[(tbase + rr) * 32 + dd];
            const unsigned sv = ((const unsigned short*)SS)[(tbase + rr) * 32 + dd];
            csT[rr * 33 + dd] = cv | (sv << 16);
        }
        __syncthreads();
        bf16_t* OUT = (sel == 0) ? qn : kn;
#pragma unroll
        for (int i = 0; i < 4; i++) {
            float c0[4], s0[4], c1[4], s1[4];
#pragma unroll
            for (int r = 0; r < 4; r++) {
                const int rl = wm + i * 16 + quad * 4 + r;
                const unsigned p0 = csT[rl * 33 + m16];
                const unsigned p1 = csT[rl * 33 + 16 + m16];
                c0[r] = bfl(p0); s0[r] = bfh(p0);
                c1[r] = bfl(p1); s1[r] = bfh(p1);
            }
            floatx4 r0, r1, r2, r3;
            float ss[4];
#pragma unroll
            for (int r = 0; r < 4; r++) {
                r0[r] = acc[i][0][r] * c0[r] - acc[i][2][r] * s0[r];
                r1[r] = acc[i][1][r] * c1[r] - acc[i][3][r] * s1[r];
                r2[r] = acc[i][0][r] * s0[r] + acc[i][2][r] * c0[r];
                r3[r] = acc[i][1][r] * s1[r] + acc[i][3][r] * c1[r];
                ss[r] = r0[r]*r0[r] + r1[r]*r1[r] + r2[r]*r2[r] + r3[r]*r3[r];
            }
#pragma unroll
            for (int r = 0; r < 4; r++) {
#pragma unroll
                for (int off = 1; off < 16; off <<= 1)
                    ss[r] += __shfl_xor(ss[r], off, 64);
            }
#pragma unroll
            for (int r = 0; r < 4; r++) {
                const float scl = rsqrtf(ss[r] * (1.f / 64.f) + 1e-6f) * 1.2f;
                const size_t rowoff = (size_t)(m0 + wm + i * 16 + quad * 4 + r) * C_
                                      + n0 + wn + m16;
                OUT[rowoff]      = (bf16_t)(r0[r] * scl);
                OUT[rowoff + 16] = (bf16_t)(r1[r] * scl);
                OUT[rowoff + 32] = (bf16_t)(r2[r] * scl);
                OUT[rowoff + 48] = (bf16_t)(r3[r] * scl);
            }
        }
    } else {
        // ---- V epilogue: gate + ve add + direct permuted store ----
        bf16_t* veT = (bf16_t*)sm;             // [128 tok][136]
        float*  gT  = (float*)(sm + 34816);    // [2][128]
        for (int idx = tid; idx < 2048; idx += 256) {
            const int rr = idx >> 4, ch = idx & 15;
            *(bf16x8*)&veT[rr * 136 + ch * 8] =
                *(const bf16x8*)&VE[(size_t)(m0 + rr) * C_ + n0 + ch * 8];
        }
        {
            const int row = tid & 127, hh = tid >> 7;
            const int head = nt * 2 + hh;
            float g = 0.f;
#pragma unroll
            for (int j2 = 0; j2 < 12; j2++)
                g += (float)X[(size_t)(m0 + row) * C_ + j2] * (float)WG[head * 12 + j2];
            gT[hh * 128 + row] = 3.f / (1.f + __expf(-g));
        }
        __syncthreads();
        const int hh2  = wn >> 6;
        const int head = nt * 2 + hh2;
        const int bb = m0 >> 11, t0 = m0 & 2047;
#pragma unroll
        for (int i = 0; i < 4; i++) {
            const floatx4 gr = *(const floatx4*)&gT[hh2 * 128 + wm + i * 16 + quad * 4];
            const int tslot = t0 + wm + (i >> 1) * 32 + quad * 8 + (i & 1) * 4;
#pragma unroll
            for (int j = 0; j < 4; j++) {
                bf16x4 o;
#pragma unroll
                for (int r = 0; r < 4; r++) {
                    const float vef = (float)veT[(wm + i * 16 + quad * 4 + r) * 136
                                                 + wn + j * 16 + m16];
                    o[r] = (bf16_t)(acc[i][j][r] + gr[r] * vef);
                }
                *(bf16x4*)&vt[((size_t)(bb * NH_ + head) * HD_ + j * 16 + m16) * T_
                              + tslot] = o;
            }
        }
    }
}

// ---------------------------------------------------------------------------
// Plain GEMM for the output projection (round-4-proven).
// ---------------------------------------------------------------------------
template <bool OUT_BF16>
__device__ __forceinline__ void gemm_bt_tile(
    const bf16_t* __restrict__ A, const bf16_t* __restrict__ Bm,
    void* __restrict__ Cout, int m0, int n0, int K, int ldc)
{
    __shared__ bf16_t As[2][128 * 32];
    __shared__ bf16_t Bs[2][128 * 32];
    const int tid  = threadIdx.x;
    const int lane = tid & 63;
    const int wid  = tid >> 6;
    const int m16  = lane & 15;
    const int quad = lane >> 4;
    const int wm   = (wid >> 1) * 64;
    const int wn   = (wid & 1) * 64;
    const int srow = lane >> 2;
    const int soct = (lane & 3) * 8;

    floatx4 acc[4][4];
#pragma unroll
    for (int i = 0; i < 4; i++)
#pragma unroll
        for (int j = 0; j < 4; j++) acc[i][j] = (floatx4){0.f, 0.f, 0.f, 0.f};

    for (int k0 = 0; k0 < K; k0 += 64) {
        const bf16_t* ga0 = &A[(size_t)(m0 + 16 * wid + srow) * K + k0 + soct];
        const bf16_t* gb0 = &Bm[(size_t)(n0 + 16 * wid + srow) * K + k0 + soct];
        gld16(ga0,                       (bf16_t*)As[0] + wid * 512);
        gld16(ga0 + (size_t)64 * K,      (bf16_t*)As[0] + wid * 512 + 2048);
        gld16(gb0,                       (bf16_t*)Bs[0] + wid * 512);
        gld16(gb0 + (size_t)64 * K,      (bf16_t*)Bs[0] + wid * 512 + 2048);
        gld16(ga0 + 32,                  (bf16_t*)As[1] + wid * 512);
        gld16(ga0 + (size_t)64 * K + 32, (bf16_t*)As[1] + wid * 512 + 2048);
        gld16(gb0 + 32,                  (bf16_t*)Bs[1] + wid * 512);
        gld16(gb0 + (size_t)64 * K + 32, (bf16_t*)Bs[1] + wid * 512 + 2048);
        __syncthreads();
#pragma unroll
        for (int half = 0; half < 2; half++) {
            bf16x8 af[4], bfr[4];
#pragma unroll
            for (int i = 0; i < 4; i++)
                af[i] = *(const bf16x8*)&As[half][(wm + i * 16 + m16) * 32 + quad * 8];
#pragma unroll
            for (int j = 0; j < 4; j++)
                bfr[j] = *(const bf16x8*)&Bs[half][(wn + j * 16 + m16) * 32 + quad * 8];
#pragma unroll
            for (int i = 0; i < 4; i++)
#pragma unroll
                for (int j = 0; j < 4; j++)
                    acc[i][j] = MFMA16(af[i], bfr[j], acc[i][j]);
        }
        __syncthreads();
    }
#pragma unroll
    for (int i = 0; i < 4; i++) {
#pragma unroll
        for (int j = 0; j < 4; j++) {
            const int colg = n0 + wn + j * 16 + m16;
#pragma unroll
            for (int r = 0; r < 4; r++) {
                const int rowg = m0 + wm + i * 16 + quad * 4 + r;
                if (OUT_BF16)
                    ((bf16_t*)Cout)[(size_t)rowg * ldc + colg] = (bf16_t)acc[i][j][r];
                else
                    ((float*)Cout)[(size_t)rowg * ldc + colg] = acc[i][j][r];
            }
        }
    }
}

__global__ __launch_bounds__(256) void gemm_proj_kernel(
    const bf16_t* __restrict__ yb, const void* wpr, const bf16_t* wpc,
    void* __restrict__ out, const void* cr)
{
    const bool f32 = (((const unsigned short*)cr)[0] == 0);
    const bf16_t* WP = f32 ? wpc : (const bf16_t*)wpr;
    if (f32)
        gemm_bt_tile<false>(yb, WP, out, blockIdx.x * 128, blockIdx.y * 128, C_, C_);
    else
        gemm_bt_tile<true>(yb, WP, out, blockIdx.x * 128, blockIdx.y * 128, C_, C_);
}

// ---------------------------------------------------------------------------
// Flash attention (round-4-proven kernel; only change: Q/K row stride is C_
// since they now live in [b][t][C]). Fixed-SMAX softmax, S^T-in-register P,
// paired-K=32 PV, register staging + explicit XOR-swizzled ds_writes.
// ---------------------------------------------------------------------------
__global__ __launch_bounds__(256, 3) void attn_kernel(
    const bf16_t* __restrict__ Q, const bf16_t* __restrict__ Km,
    const bf16_t* __restrict__ Vtg, bf16_t* __restrict__ Y,
    const int* __restrict__ wl)
{
    const int bx   = blockIdx.x;
    const int bh   = blockIdx.y;
    const int gsel = bh >> 4;
    int qblk;
    if (gsel == 0)      qblk = bx;
    else if (gsel == 1) qblk = 15 - bx;
    else                qblk = (int)((0xECA8642013579BDFull >> (bx * 4)) & 0xF);
    const int q0 = qblk * 128;
    const int b  = bh / NH_;
    const int h  = bh % NH_;
    const int window = wl[0];
    const int tid  = threadIdx.x;
    const int wid  = tid >> 6;
    const int lane = tid & 63;
    const int m16  = lane & 15;
    const int quad = lane >> 4;
    const int qw   = q0 + wid * 32;

    const bf16_t* Qb = Q + (size_t)b * T_ * C_ + h * HD_;   // row stride C_
    const bf16_t* Kb = Km + (size_t)b * T_ * C_ + h * HD_;
    const bf16_t* Vb = Vtg + (size_t)bh * HD_ * T_;         // [d][t-perm]

    __shared__ bf16_t Ks[2][64 * 64];
    __shared__ bf16_t Vs[2][64 * 64];

    bf16x8 qf[2][2];
#pragma unroll
    for (int mt = 0; mt < 2; mt++)
#pragma unroll
        for (int ks = 0; ks < 2; ks++)
            qf[mt][ks] = *(const bf16x8*)
                &Qb[(size_t)(qw + mt * 16 + m16) * C_ + ks * 32 + quad * 8];

    // staging: thread -> (row = tid>>2, two octets), XOR-swizzled columns
    const int srow = tid >> 2;
    const int soct = tid & 3;
    const int g0   = 2 * soct, g1 = 2 * soct + 1;
    const int kd0  = srow * 64 + ((g0 ^ (srow & 7)) << 3);
    const int kd1  = srow * 64 + ((g1 ^ (srow & 7)) << 3);
    int rsw[2];
#pragma unroll
    for (int ks = 0; ks < 2; ks++)
        rsw[ks] = (((ks * 4 + quad) ^ (m16 & 7)) << 3);

    int lo = q0 - window;
    if (lo < 0) lo = 0;
    lo &= ~63;
    const int nch = (q0 + 128 - lo) >> 6;

    floatx4 accO[2][4];
#pragma unroll
    for (int mt = 0; mt < 2; mt++)
#pragma unroll
        for (int dt = 0; dt < 4; dt++) accO[mt][dt] = (floatx4){0.f, 0.f, 0.f, 0.f};
    float lsum[2] = {0.f, 0.f};
    const bf16x4 zero4 = {(bf16_t)0.f, (bf16_t)0.f, (bf16_t)0.f, (bf16_t)0.f};

    // preload + stage chunk 0
    bf16x8 ka0 = *(const bf16x8*)&Kb[(size_t)(lo + srow) * C_ + g0 * 8];
    bf16x8 ka1 = *(const bf16x8*)&Kb[(size_t)(lo + srow) * C_ + g1 * 8];
    bf16x8 va0 = *(const bf16x8*)&Vb[(size_t)srow * T_ + lo + g0 * 8];
    bf16x8 va1 = *(const bf16x8*)&Vb[(size_t)srow * T_ + lo + g1 * 8];
    *(bf16x8*)&Ks[0][kd0] = ka0;
    *(bf16x8*)&Ks[0][kd1] = ka1;
    *(bf16x8*)&Vs[0][kd0] = va0;
    *(bf16x8*)&Vs[0][kd1] = va1;

    for (int ic = 0; ic < nch; ic++) {
        const int kc = lo + ic * 64;
        const bool more = (ic + 1 < nch);
        if (more) {
            const int kn2 = kc + 64;
            ka0 = *(const bf16x8*)&Kb[(size_t)(kn2 + srow) * C_ + g0 * 8];
            ka1 = *(const bf16x8*)&Kb[(size_t)(kn2 + srow) * C_ + g1 * 8];
            va0 = *(const bf16x8*)&Vb[(size_t)srow * T_ + kn2 + g0 * 8];
            va1 = *(const bf16x8*)&Vb[(size_t)srow * T_ + kn2 + g1 * 8];
        }
        __syncthreads();
        const int buf = ic & 1;

        const bool skip = (kc > qw + 31) || (kc + 63 < qw - window);
        if (!skip) {
            bf16x8 kf[4][2];
#pragma unroll
            for (int nt = 0; nt < 4; nt++) {
                const int rb = (nt * 16 + m16) * 64;
                kf[nt][0] = *(const bf16x8*)&Ks[buf][rb + rsw[0]];
                kf[nt][1] = *(const bf16x8*)&Ks[buf][rb + rsw[1]];
            }
            bf16x4 pk[2][4];
            unsigned livemask = 0;
#pragma unroll
            for (int mt = 0; mt < 2; mt++) {
                const int qmin = qw + mt * 16, qmax = qmin + 15;
                float lacc = 0.f;
#pragma unroll
                for (int nt = 0; nt < 4; nt++) {
                    const int kmin = kc + nt * 16, kmax = kmin + 15;
                    if (kmin > qmax || kmax < qmin - window) {
                        pk[mt][nt] = zero4;
                        continue;
                    }
                    livemask |= 1u << (mt * 4 + nt);
                    floatx4 z = (floatx4){0.f, 0.f, 0.f, 0.f};
                    z = MFMA16(kf[nt][0], qf[mt][0], z);
                    z = MFMA16(kf[nt][1], qf[mt][1], z);
                    const bool edge = (kmax > qmin) || (kmin < qmax - window);
                    const int query = qmin + m16;
                    bf16x4 t4;
#pragma unroll
                    for (int r = 0; r < 4; r++) {
                        float p = __builtin_amdgcn_exp2f(
                            fmaf(z[r], SM_C1, SM_C2));
                        if (edge) {
                            const int key = kmin + quad * 4 + r;
                            const bool ok = (key <= query) &&
                                            (query - key <= window);
                            p = ok ? p : 0.f;
                        }
                        t4[r] = (bf16_t)p;
                        lacc += p;
                    }
                    pk[mt][nt] = t4;
                }
                lsum[mt] += lacc;
            }
#pragma unroll
            for (int pr = 0; pr < 2; pr++) {
                const unsigned pm0 = (livemask >> (2 * pr)) & 3u;
                const unsigned pm1 = (livemask >> (4 + 2 * pr)) & 3u;
                if (!(pm0 | pm1)) continue;
                const bf16x8 pa0 = __builtin_shufflevector(
                    pk[0][2 * pr], pk[0][2 * pr + 1], 0, 1, 2, 3, 4, 5, 6, 7);
                const bf16x8 pa1 = __builtin_shufflevector(
                    pk[1][2 * pr], pk[1][2 * pr + 1], 0, 1, 2, 3, 4, 5, 6, 7);
                const int vco = (((pr * 4 + quad) ^ (m16 & 7)) << 3);
#pragma unroll
                for (int dt = 0; dt < 4; dt++) {
                    const bf16x8 vf = *(const bf16x8*)
                        &Vs[buf][(dt * 16 + m16) * 64 + vco];
                    if (pm0) accO[0][dt] = MFMA16(pa0, vf, accO[0][dt]);
                    if (pm1) accO[1][dt] = MFMA16(pa1, vf, accO[1][dt]);
                }
            }
        }

        if (more) {
            const int nb = buf ^ 1;
            *(bf16x8*)&Ks[nb][kd0] = ka0;
            *(bf16x8*)&Ks[nb][kd1] = ka1;
            *(bf16x8*)&Vs[nb][kd0] = va0;
            *(bf16x8*)&Vs[nb][kd1] = va1;
        }
    }

#pragma unroll
    for (int mt = 0; mt < 2; mt++) {
        float red = lsum[mt];
        red += __shfl_xor(red, 16, 64);
        red += __shfl_xor(red, 32, 64);
#pragma unroll
        for (int r = 0; r < 4; r++) {
            const float lq  = __shfl(red, quad * 4 + r, 64);
            const float inv = 1.f / lq;
            const int   tq  = qw + mt * 16 + quad * 4 + r;
#pragma unroll
            for (int dt = 0; dt < 4; dt++)
                Y[((size_t)b * T_ + tq) * C_ + h * HD_ + dt * 16 + m16] =
                    (bf16_t)(accO[mt][dt][r] * inv);
        }
    }
}

// ---------------------------------------------------------------------------
extern "C" void kernel_launch(void* const* d_in, const int* in_sizes, int n_in,
                              void* d_out, int out_size, void* d_ws, size_t ws_size,
                              hipStream_t stream)
{
    const void* x_raw   = d_in[0];
    const void* ve_raw  = d_in[1];
    const void* cos_raw = d_in[2];
    const void* sin_raw = d_in[3];
    const void* wq_raw  = d_in[4];
    const void* wk_raw  = d_in[5];
    const void* wv_raw  = d_in[6];
    const void* wp_raw  = d_in[7];
    const void* wg_raw  = d_in[8];
    const int*  wl      = (const int*)d_in[9];

    const size_t NTC = (size_t)B_ * T_ * C_;  // 6291456
    const size_t WSZ = (size_t)C_ * C_;       // 589824

    bf16_t* ws  = (bf16_t*)d_ws;
    bf16_t* xb  = ws;                 // NTC   (fp32-cvt targets)
    bf16_t* veb = xb + NTC;           // NTC
    bf16_t* cb  = veb + NTC;          // 65536
    bf16_t* sb  = cb + T_ * 32;       // 65536
    bf16_t* wqb = sb + T_ * 32;       // WSZ x4
    bf16_t* wkb = wqb + WSZ;
    bf16_t* wvb = wkb + WSZ;
    bf16_t* wpb = wvb + WSZ;
    bf16_t* wgb = wpb + WSZ;          // 144 (pad 256)
    bf16_t* qn  = wgb + 256;          // NTC  rope+rms Q  [b][t][C]
    bf16_t* kn  = qn + NTC;           // NTC  rope+rms K  [b][t][C]
    bf16_t* vt  = kn + NTC;           // NTC  V^T [bh][d][t-perm]
    bf16_t* yb  = vt + NTC;           // NTC  attention out [b][t][C]

    cvt_all_kernel<<<dim3(128, 9), 256, 0, stream>>>(
        x_raw, ve_raw, cos_raw, sin_raw, wq_raw, wk_raw, wv_raw, wp_raw, wg_raw,
        xb, veb, cb, sb, wqb, wkb, wvb, wpb, wgb);

    gemm_qkv_fused<<<dim3(64, 18), 256, 0, stream>>>(
        x_raw, xb, wq_raw, wqb, wk_raw, wkb, wv_raw, wvb,
        cos_raw, cb, sin_raw, sb, ve_raw, veb, wg_raw, wgb,
        qn, kn, vt);

    attn_kernel<<<dim3(16, 48), 256, 0, stream>>>(qn, kn, vt, yb, wl);

    gemm_proj_kernel<<<dim3(64, 6), 256, 0, stream>>>(yb, wp_raw, wpb, d_out, cos_raw);
}